// Round 7
// baseline (249.220 us; speedup 1.0000x reference)
//
#include <hip/hip_runtime.h>

#define B_   8
#define N_   307
#define BN   (B_ * N_)          // 2456 blocks
#define OUT_ELEMS (BN * 64 * 64)

typedef float f32x4 __attribute__((ext_vector_type(4)));
typedef short s16x8 __attribute__((ext_vector_type(8)));
typedef unsigned int u32x4 __attribute__((ext_vector_type(4)));

__device__ __forceinline__ unsigned short f2bf(float x) {
    unsigned int u = __builtin_bit_cast(unsigned int, x);
    u += 0x7FFFu + ((u >> 16) & 1u);        // round-to-nearest-even
    return (unsigned short)(u >> 16);
}

// XOR-swizzle on 16B frag rows (G4 / m201): bijective within 8-row groups.
__device__ __forceinline__ int swz(int row) { return row ^ ((row >> 3) & 7); }

__device__ __forceinline__ s16x8 ldfrag(const unsigned short* p) {
    return *reinterpret_cast<const s16x8*>(p);
}

__device__ __forceinline__ s16x8 cvt8(float4 lo, float4 hi) {
    s16x8 f;
    f[0] = (short)f2bf(lo.x); f[1] = (short)f2bf(lo.y);
    f[2] = (short)f2bf(lo.z); f[3] = (short)f2bf(lo.w);
    f[4] = (short)f2bf(hi.x); f[5] = (short)f2bf(hi.y);
    f[6] = (short)f2bf(hi.z); f[7] = (short)f2bf(hi.w);
    return f;
}

// 64x64 row-major fp32 (K x N) global -> bf16 B-operand frag layout (swizzled)
__device__ __forceinline__ void stage_B(const float* __restrict__ src,
                                        unsigned short* dst, int tid) {
    const float4* s4 = reinterpret_cast<const float4*>(src);
#pragma unroll
    for (int i = 0; i < 4; ++i) {
        int idx = i * 256 + tid;
        float4 v = s4[idx];
        int k  = idx >> 4;
        int n0 = (idx & 15) << 2;
        int ki = k >> 5;
        int qd = (k >> 3) & 3;
        int j  = k & 7;
        float vv[4] = {v.x, v.y, v.z, v.w};
#pragma unroll
        for (int c = 0; c < 4; ++c) {
            int n = n0 + c;
            int row = ((n >> 4) * 2 + ki) * 64 + (qd << 4) + (n & 15);
            dst[(swz(row) << 3) + j] = f2bf(vv[c]);
        }
    }
}

__global__ __launch_bounds__(256, 6) void mta_kernel(
    const float* __restrict__ Xq, const float* __restrict__ Xk,
    const float* __restrict__ Xv, const float* __restrict__ maskp,
    const float* __restrict__ res, const float* __restrict__ Wq,
    const float* __restrict__ Wk, const float* __restrict__ Wv,
    const float* __restrict__ Wfc, const float* __restrict__ lnS,
    const float* __restrict__ lnB, float* __restrict__ out,
    float* __restrict__ scores_out)
{
    // 24KB LDS -> 6 blocks/CU. Q frags never touch LDS: Q projection computed
    // operand-swapped (C[e][q]) so each wave holds its own head-Q packed in 8
    // VGPRs; attention A-frag rebuilt with 4 __shfl per head.
    // q-row-tiled attention (R5 pattern: coalesced rows, inner nt loop keeps
    // both halves of each 128B scores line written close in time).
    // Barriers: 1/head (same-wave sWA frag write->PV read needs none).
    __shared__ __align__(16) unsigned char smem[24576];
    unsigned short* sKf = (unsigned short*)(smem);           // 8KB scores B-frags (K) / wS alias / ctx frags (fc)
    unsigned short* sVf = (unsigned short*)(smem + 8192);    // 8KB PV B-frags (V)
    unsigned short* sWA = (unsigned short*)(smem + 16384);   // 8KB W frags / attn A-frags / h0 wS

    const int bn   = blockIdx.x;
    const int tid  = threadIdx.x;
    const int w    = tid >> 6;
    const int lane = tid & 63;
    const int quad = lane >> 4;
    const int l16  = lane & 15;
    const size_t base64 = (size_t)bn * 4096;

    // q-tiled per-lane tile offset: element (q = w*16+quad*4+r, col = nt*16+l16)
    const int toff = (w * 16 + quad * 4) * 64 + l16;

    // mask bits for this thread's 4 q-rows
    float4 mv = *reinterpret_cast<const float4*>(maskp + bn * 64 + w * 16 + quad * 4);
    bool bm[4] = {mv.x > 0.5f, mv.y > 0.5f, mv.z > 0.5f, mv.w > 0.5f};

    // res double-buffer; prefetch head 0 now (lands under projections)
    float rA[4][4], rB[4][4];
    {
        const float* rp = res + (((size_t)(bn * 4)) << 12) + toff;
#pragma unroll
        for (int nt = 0; nt < 4; ++nt)
#pragma unroll
            for (int r = 0; r < 4; ++r)
                rA[nt][r] = rp[r * 64 + nt * 16];
    }

    // packed Q (C[e][q] layout): per e-tile (= head) 2 u32 of bf16x2
    unsigned qpk[4][2];

    // ---------------- Projections: Q (swapped, scaled 1/4), K, V ----------------
#pragma unroll 1
    for (int pj = 0; pj < 3; ++pj) {
        const float* Xs = (pj == 0) ? Xq : (pj == 1) ? Xk : Xv;
        const float* Ws = (pj == 0) ? Wq : (pj == 1) ? Wk : Wv;
        // X A-frags direct from global: lane holds X[m=w*16+l16][k=quad*8+ki*32 ..+7]
        const float* p = Xs + base64 + (w * 16 + l16) * 64 + quad * 8;
        float4 x0 = *(const float4*)(p);      float4 x1 = *(const float4*)(p + 4);
        float4 x2 = *(const float4*)(p + 32); float4 x3 = *(const float4*)(p + 36);
        stage_B(Ws, sWA, tid);
        __syncthreads();
        s16x8 a0 = cvt8(x0, x1);
        s16x8 a1 = cvt8(x2, x3);
#pragma unroll
        for (int nt = 0; nt < 4; ++nt) {
            f32x4 acc = {0.f, 0.f, 0.f, 0.f};
            s16x8 b0 = ldfrag(sWA + (swz((nt * 2 + 0) * 64 + lane) << 3));
            s16x8 b1 = ldfrag(sWA + (swz((nt * 2 + 1) * 64 + lane) << 3));
            if (pj == 0) {
                // swapped: D[e][q] = sum_f Wq[f][e] * X[q][f]
                acc = __builtin_amdgcn_mfma_f32_16x16x32_bf16(b0, a0, acc, 0, 0, 0);
                acc = __builtin_amdgcn_mfma_f32_16x16x32_bf16(b1, a1, acc, 0, 0, 0);
                // lane (quad,l16) holds Q[q=w*16+l16][e=nt*16+quad*4+r]; pack *0.25
                qpk[nt][0] = (unsigned)f2bf(acc[0] * 0.25f)
                           | ((unsigned)f2bf(acc[1] * 0.25f) << 16);
                qpk[nt][1] = (unsigned)f2bf(acc[2] * 0.25f)
                           | ((unsigned)f2bf(acc[3] * 0.25f) << 16);
            } else {
                acc = __builtin_amdgcn_mfma_f32_16x16x32_bf16(a0, b0, acc, 0, 0, 0);
                acc = __builtin_amdgcn_mfma_f32_16x16x32_bf16(a1, b1, acc, 0, 0, 0);
                if (pj == 1) {      // K -> scores B-frag layout
#pragma unroll
                    for (int r = 0; r < 4; ++r) {
                        int rowk = (nt * 4 + w) * 32 + ((l16 >> 3) << 4) + quad * 4 + r;
                        sKf[(swz(rowk) << 3) + (l16 & 7)] = f2bf(acc[r]);
                    }
                } else {            // V -> PV B-frag layout (nt == head)
#pragma unroll
                    for (int r = 0; r < 4; ++r) {
                        int kk = w * 16 + quad * 4 + r;
                        int rowv = (nt * 2 + (kk >> 5)) * 64 + (((kk >> 3) & 3) << 4) + l16;
                        sVf[(swz(rowv) << 3) + (kk & 7)] = f2bf(acc[r]);
                    }
                }
            }
        }
        __syncthreads();
    }

    // ---------------- Attention (q-row-tiled; 1 barrier/head) ----------------
    f32x4 ctx[4];
#pragma unroll
    for (int h = 0; h < 4; ++h) ctx[h] = {0.f, 0.f, 0.f, 0.f};

    float xres[4][4], scl[4], bia[4];   // fc prefetch, loaded during head 3

    const s16x8 zf = {0, 0, 0, 0, 0, 0, 0, 0};
#pragma unroll
    for (int h = 0; h < 4; ++h) {
        const size_t sbase = ((size_t)(bn * 4 + h)) << 12;
        float (&rc)[4][4] = (h & 1) ? rB : rA;   // current head's res
        float (&rn)[4][4] = (h & 1) ? rA : rB;   // next head's res
        if (h < 3) {
            const float* rp = res + sbase + 4096 + toff;
#pragma unroll
            for (int nt = 0; nt < 4; ++nt)
#pragma unroll
                for (int r = 0; r < 4; ++r)
                    rn[nt][r] = rp[r * 64 + nt * 16];
        } else {                                 // fc operand prefetch
            const float* xp = Xq + base64 + toff;
#pragma unroll
            for (int nt = 0; nt < 4; ++nt) {
#pragma unroll
                for (int r = 0; r < 4; ++r) xres[nt][r] = xp[r * 64 + nt * 16];
                scl[nt] = lnS[nt * 16 + l16];
                bia[nt] = lnB[nt * 16 + l16];
            }
        }

        // rebuild this head's Q A-frag from packed regs: consumer lane c(<32)
        // element j: Q(q=w*16+(c&15), e=(c>>4)*8+j) lives at producer
        // p = (c&16)*2 + (c&15) (j=0..3) / p+16 (j=4..7), word = j>>1.
        s16x8 aq;
        {
            int p0 = ((lane & 16) << 1) + l16;
            unsigned w0 = __shfl(qpk[h][0], p0, 64);
            unsigned w1 = __shfl(qpk[h][1], p0, 64);
            unsigned w2 = __shfl(qpk[h][0], p0 + 16, 64);
            unsigned w3 = __shfl(qpk[h][1], p0 + 16, 64);
            if (lane >= 32) { w0 = 0; w1 = 0; w2 = 0; w3 = 0; }
            u32x4 uv = {w0, w1, w2, w3};
            aq = __builtin_bit_cast(s16x8, uv);
        }

        // scores rows w*16..+15: res folded in as MFMA C-in. K=16 zero-padded.
        float sv[4][4], Sw[4];
#pragma unroll
        for (int nt = 0; nt < 4; ++nt) {
            s16x8 bk = zf;
            if (lane < 32) bk = ldfrag(sKf + (swz((h * 4 + nt) * 32 + lane) << 3));
            f32x4 cin = {rc[nt][0], rc[nt][1], rc[nt][2], rc[nt][3]};
            f32x4 t = __builtin_amdgcn_mfma_f32_16x16x32_bf16(aq, bk, cin, 0, 0, 0);
#pragma unroll
            for (int r = 0; r < 4; ++r) {
                float s = bm[r] ? -1e9f : t[r];
                scores_out[sbase + toff + r * 64 + nt * 16] = s;
                sv[nt][r] = __expf(s);      // masked rows -> exp underflows to 0
            }
            float e = sv[nt][0] + sv[nt][1] + sv[nt][2] + sv[nt][3];
            e += __shfl_xor(e, 16, 64);
            e += __shfl_xor(e, 32, 64);
            Sw[nt] = e;
        }
        // cross-wave column-sum combine. wS region: h0 -> sWA[0:1KB] (extra
        // barrier below); h>=1 -> head (h-1)'s dead K region sKf[(h-1)*2KB].
        float* wS = (h == 0) ? (float*)(smem + 16384) : (float*)(smem + (h - 1) * 2048);
        if (quad == 0) {
#pragma unroll
            for (int nt = 0; nt < 4; ++nt) wS[(nt * 16 + l16) * 4 + w] = Sw[nt];
        }
        __syncthreads();   // the head's single barrier

        float inv[4];
#pragma unroll
        for (int nt = 0; nt < 4; ++nt) {
            float4 vs = *reinterpret_cast<float4*>(&wS[(nt * 16 + l16) * 4]);
            inv[nt] = 1.0f / (vs.x + vs.y + vs.z + vs.w);
        }
        if (h == 0) __syncthreads();   // wS aliases sWA (wave 0's frag rows) at h0 only

        // attn -> PV A-frag layout; wave writes ONLY its own rows (w*2, w*2+1)
#pragma unroll
        for (int nt = 0; nt < 4; ++nt) {
            int k  = nt * 16 + l16;
            int rw = (w * 2 + (k >> 5)) * 64 + (((k >> 3) & 3) << 4) + quad * 4;
#pragma unroll
            for (int r = 0; r < 4; ++r)
                sWA[(swz(rw + r) << 3) + (k & 7)] = f2bf(sv[nt][r] * inv[nt]);
        }
        // PV immediately: same-wave ds write->read, no barrier needed
#pragma unroll
        for (int ki = 0; ki < 2; ++ki) {
            s16x8 ap = ldfrag(sWA + (swz((w * 2 + ki) * 64 + lane) << 3));
            s16x8 bv = ldfrag(sVf + (swz((h * 2 + ki) * 64 + lane) << 3));
            ctx[h] = __builtin_amdgcn_mfma_f32_16x16x32_bf16(ap, bv, ctx[h], 0, 0, 0);
        }
    }
    __syncthreads();   // all attention LDS reads done; sKf/sWA reusable

    // ---------------- fc + residual + layernorm ----------------
    // ctx -> fc A-frag layout into sKf (dead); Wfc B-frags into sWA (dead)
#pragma unroll
    for (int hh = 0; hh < 4; ++hh) {
        int c    = hh * 16 + l16;
        int rowb = (w * 2 + (c >> 5)) * 64 + (((c >> 3) & 3) << 4) + quad * 4;
#pragma unroll
        for (int r = 0; r < 4; ++r)
            sKf[(swz(rowb + r) << 3) + (c & 7)] = f2bf(ctx[hh][r]);
    }
    stage_B(Wfc, sWA, tid);
    __syncthreads();

    f32x4 oacc[4];
    {
        s16x8 a0 = ldfrag(sKf + (swz((w * 2 + 0) * 64 + lane) << 3));
        s16x8 a1 = ldfrag(sKf + (swz((w * 2 + 1) * 64 + lane) << 3));
#pragma unroll
        for (int nt = 0; nt < 4; ++nt) {
            f32x4 a = {0.f, 0.f, 0.f, 0.f};
            s16x8 b0 = ldfrag(sWA + (swz((nt * 2 + 0) * 64 + lane) << 3));
            s16x8 b1 = ldfrag(sWA + (swz((nt * 2 + 1) * 64 + lane) << 3));
            a = __builtin_amdgcn_mfma_f32_16x16x32_bf16(a0, b0, a, 0, 0, 0);
            a = __builtin_amdgcn_mfma_f32_16x16x32_bf16(a1, b1, a, 0, 0, 0);
            oacc[nt] = a;
        }
    }

#pragma unroll
    for (int r = 0; r < 4; ++r) {
        float px[4], sum = 0.f, sq = 0.f;
#pragma unroll
        for (int nt = 0; nt < 4; ++nt) {
            float x = oacc[nt][r] + xres[nt][r];
            px[nt] = x; sum += x; sq += x * x;
        }
#pragma unroll
        for (int m = 1; m <= 8; m <<= 1) {
            sum += __shfl_xor(sum, m, 64);
            sq  += __shfl_xor(sq,  m, 64);
        }
        float mu   = sum * 0.015625f;
        float var  = sq * 0.015625f - mu * mu;
        float rstd = rsqrtf(var + 1e-5f);
#pragma unroll
        for (int nt = 0; nt < 4; ++nt) {
            out[base64 + toff + r * 64 + nt * 16] = (px[nt] - mu) * rstd * scl[nt] + bia[nt];
        }
    }
}

extern "C" void kernel_launch(void* const* d_in, const int* in_sizes, int n_in,
                              void* d_out, int out_size, void* d_ws, size_t ws_size,
                              hipStream_t stream) {
    const float* Xq   = (const float*)d_in[0];
    const float* Xk   = (const float*)d_in[1];
    const float* Xv   = (const float*)d_in[2];
    const float* msk  = (const float*)d_in[3];
    const float* res  = (const float*)d_in[4];
    const float* Wq   = (const float*)d_in[5];
    const float* Wk   = (const float*)d_in[6];
    const float* Wv   = (const float*)d_in[7];
    const float* Wfc  = (const float*)d_in[8];
    const float* lnS  = (const float*)d_in[9];
    const float* lnB  = (const float*)d_in[10];
    float* out    = (float*)d_out;
    float* scores = out + OUT_ELEMS;
    mta_kernel<<<BN, 256, 0, stream>>>(Xq, Xk, Xv, msk, res, Wq, Wk, Wv, Wfc,
                                       lnS, lnB, out, scores);
}

// Round 8
// 105.972 us; speedup vs baseline: 2.3518x; 2.3518x over previous
//
#include <hip/hip_runtime.h>

#define B_   8
#define N_   307
#define BN   (B_ * N_)          // 2456 blocks
#define OUT_ELEMS (BN * 64 * 64)

typedef float f32x4 __attribute__((ext_vector_type(4)));
typedef short s16x8 __attribute__((ext_vector_type(8)));
typedef unsigned int u32x4 __attribute__((ext_vector_type(4)));

__device__ __forceinline__ unsigned short f2bf(float x) {
    unsigned int u = __builtin_bit_cast(unsigned int, x);
    u += 0x7FFFu + ((u >> 16) & 1u);        // round-to-nearest-even
    return (unsigned short)(u >> 16);
}

// XOR-swizzle on 16B frag rows (G4 / m201): bijective within 8-row groups.
__device__ __forceinline__ int swz(int row) { return row ^ ((row >> 3) & 7); }

__device__ __forceinline__ s16x8 ldfrag(const unsigned short* p) {
    return *reinterpret_cast<const s16x8*>(p);
}

__device__ __forceinline__ s16x8 cvt8(float4 lo, float4 hi) {
    s16x8 f;
    f[0] = (short)f2bf(lo.x); f[1] = (short)f2bf(lo.y);
    f[2] = (short)f2bf(lo.z); f[3] = (short)f2bf(lo.w);
    f[4] = (short)f2bf(hi.x); f[5] = (short)f2bf(hi.y);
    f[6] = (short)f2bf(hi.z); f[7] = (short)f2bf(hi.w);
    return f;
}

// 64x64 row-major fp32 (K x N) global -> bf16 B-operand frag layout (swizzled)
__device__ __forceinline__ void stage_B(const float* __restrict__ src,
                                        unsigned short* dst, int tid) {
    const float4* s4 = reinterpret_cast<const float4*>(src);
#pragma unroll
    for (int i = 0; i < 4; ++i) {
        int idx = i * 256 + tid;
        float4 v = s4[idx];
        int k  = idx >> 4;
        int n0 = (idx & 15) << 2;
        int ki = k >> 5;
        int qd = (k >> 3) & 3;
        int j  = k & 7;
        float vv[4] = {v.x, v.y, v.z, v.w};
#pragma unroll
        for (int c = 0; c < 4; ++c) {
            int n = n0 + c;
            int row = ((n >> 4) * 2 + ki) * 64 + (qd << 4) + (n & 15);
            dst[(swz(row) << 3) + j] = f2bf(vv[c]);
        }
    }
}

__global__ __launch_bounds__(256, 4) void mta_kernel(
    const float* __restrict__ Xq, const float* __restrict__ Xk,
    const float* __restrict__ Xv, const float* __restrict__ maskp,
    const float* __restrict__ res, const float* __restrict__ Wq,
    const float* __restrict__ Wk, const float* __restrict__ Wv,
    const float* __restrict__ Wfc, const float* __restrict__ lnS,
    const float* __restrict__ lnB, float* __restrict__ out,
    float* __restrict__ scores_out)
{
    // 24KB LDS -> 6 blocks/CU possible (R7 proved occupancy 55%).
    // bounds (256,4): VGPR cap 128 -> NO spill (R7's (256,6) cap ~85 spilled:
    // VGPR=40, +470MB scratch traffic).
    // Q frags never touch LDS: Q projection operand-swapped (C[e][q]) -> each
    // wave holds its head-Q packed in 8 VGPRs; A-frag rebuilt w/ 4 shfl/head.
    // q-row-tiled attention (R5 pattern: coalesced complete rows, inner nt
    // loop keeps both 64B halves of each 128B line close in time).
    // 1 barrier/head (same-wave sWA frag write->PV read needs none).
    __shared__ __align__(16) unsigned char smem[24576];
    unsigned short* sKf = (unsigned short*)(smem);           // 8KB scores B-frags (K) / wS alias / ctx frags (fc)
    unsigned short* sVf = (unsigned short*)(smem + 8192);    // 8KB PV B-frags (V)
    unsigned short* sWA = (unsigned short*)(smem + 16384);   // 8KB W frags / attn A-frags / h0 wS

    const int bn   = blockIdx.x;
    const int tid  = threadIdx.x;
    const int w    = tid >> 6;
    const int lane = tid & 63;
    const int quad = lane >> 4;
    const int l16  = lane & 15;
    const size_t base64 = (size_t)bn * 4096;

    // q-tiled per-lane tile offset: element (q = w*16+quad*4+r, col = nt*16+l16)
    const int toff = (w * 16 + quad * 4) * 64 + l16;

    // mask bits for this thread's 4 q-rows
    float4 mv = *reinterpret_cast<const float4*>(maskp + bn * 64 + w * 16 + quad * 4);
    bool bm[4] = {mv.x > 0.5f, mv.y > 0.5f, mv.z > 0.5f, mv.w > 0.5f};

    // res double-buffer; prefetch head 0 now (lands under projections)
    float rA[4][4], rB[4][4];
    {
        const float* rp = res + (((size_t)(bn * 4)) << 12) + toff;
#pragma unroll
        for (int nt = 0; nt < 4; ++nt)
#pragma unroll
            for (int r = 0; r < 4; ++r)
                rA[nt][r] = rp[r * 64 + nt * 16];
    }

    // packed Q (C[e][q] layout): per e-tile (= head) 2 u32 of bf16x2
    unsigned qpk[4][2];

    // ---------------- Projections: Q (swapped, scaled 1/4), K, V ----------------
#pragma unroll 1
    for (int pj = 0; pj < 3; ++pj) {
        const float* Xs = (pj == 0) ? Xq : (pj == 1) ? Xk : Xv;
        const float* Ws = (pj == 0) ? Wq : (pj == 1) ? Wk : Wv;
        // X A-frags direct from global: lane holds X[m=w*16+l16][k=quad*8+ki*32 ..+7]
        const float* p = Xs + base64 + (w * 16 + l16) * 64 + quad * 8;
        float4 x0 = *(const float4*)(p);      float4 x1 = *(const float4*)(p + 4);
        float4 x2 = *(const float4*)(p + 32); float4 x3 = *(const float4*)(p + 36);
        stage_B(Ws, sWA, tid);
        __syncthreads();
        s16x8 a0 = cvt8(x0, x1);
        s16x8 a1 = cvt8(x2, x3);
#pragma unroll
        for (int nt = 0; nt < 4; ++nt) {
            f32x4 acc = {0.f, 0.f, 0.f, 0.f};
            s16x8 b0 = ldfrag(sWA + (swz((nt * 2 + 0) * 64 + lane) << 3));
            s16x8 b1 = ldfrag(sWA + (swz((nt * 2 + 1) * 64 + lane) << 3));
            if (pj == 0) {
                // swapped: D[e][q] = sum_f Wq[f][e] * X[q][f]
                acc = __builtin_amdgcn_mfma_f32_16x16x32_bf16(b0, a0, acc, 0, 0, 0);
                acc = __builtin_amdgcn_mfma_f32_16x16x32_bf16(b1, a1, acc, 0, 0, 0);
                // lane (quad,l16) holds Q[q=w*16+l16][e=nt*16+quad*4+r]; pack *0.25
                qpk[nt][0] = (unsigned)f2bf(acc[0] * 0.25f)
                           | ((unsigned)f2bf(acc[1] * 0.25f) << 16);
                qpk[nt][1] = (unsigned)f2bf(acc[2] * 0.25f)
                           | ((unsigned)f2bf(acc[3] * 0.25f) << 16);
            } else {
                acc = __builtin_amdgcn_mfma_f32_16x16x32_bf16(a0, b0, acc, 0, 0, 0);
                acc = __builtin_amdgcn_mfma_f32_16x16x32_bf16(a1, b1, acc, 0, 0, 0);
                if (pj == 1) {      // K -> scores B-frag layout
#pragma unroll
                    for (int r = 0; r < 4; ++r) {
                        int rowk = (nt * 4 + w) * 32 + ((l16 >> 3) << 4) + quad * 4 + r;
                        sKf[(swz(rowk) << 3) + (l16 & 7)] = f2bf(acc[r]);
                    }
                } else {            // V -> PV B-frag layout (nt == head)
#pragma unroll
                    for (int r = 0; r < 4; ++r) {
                        int kk = w * 16 + quad * 4 + r;
                        int rowv = (nt * 2 + (kk >> 5)) * 64 + (((kk >> 3) & 3) << 4) + l16;
                        sVf[(swz(rowv) << 3) + (kk & 7)] = f2bf(acc[r]);
                    }
                }
            }
        }
        __syncthreads();
    }

    // ---------------- Attention (q-row-tiled; 1 barrier/head) ----------------
    f32x4 ctx[4];
#pragma unroll
    for (int h = 0; h < 4; ++h) ctx[h] = {0.f, 0.f, 0.f, 0.f};

    const s16x8 zf = {0, 0, 0, 0, 0, 0, 0, 0};
#pragma unroll
    for (int h = 0; h < 4; ++h) {
        const size_t sbase = ((size_t)(bn * 4 + h)) << 12;
        float (&rc)[4][4] = (h & 1) ? rB : rA;   // current head's res
        float (&rn)[4][4] = (h & 1) ? rA : rB;   // next head's res
        if (h < 3) {
            const float* rp = res + sbase + 4096 + toff;
#pragma unroll
            for (int nt = 0; nt < 4; ++nt)
#pragma unroll
                for (int r = 0; r < 4; ++r)
                    rn[nt][r] = rp[r * 64 + nt * 16];
        }

        // rebuild this head's Q A-frag from packed regs: consumer lane c(<32)
        // element j: Q(q=w*16+(c&15), e=(c>>4)*8+j) lives at producer
        // p = (c&16)*2 + (c&15) (j=0..3) / p+16 (j=4..7), word = j>>1.
        s16x8 aq;
        {
            int p0 = ((lane & 16) << 1) + l16;
            unsigned w0 = __shfl(qpk[h][0], p0, 64);
            unsigned w1 = __shfl(qpk[h][1], p0, 64);
            unsigned w2 = __shfl(qpk[h][0], p0 + 16, 64);
            unsigned w3 = __shfl(qpk[h][1], p0 + 16, 64);
            if (lane >= 32) { w0 = 0; w1 = 0; w2 = 0; w3 = 0; }
            u32x4 uv = {w0, w1, w2, w3};
            aq = __builtin_bit_cast(s16x8, uv);
        }

        // scores rows w*16..+15: res folded in as MFMA C-in. K=16 zero-padded.
        float sv[4][4], Sw[4];
#pragma unroll
        for (int nt = 0; nt < 4; ++nt) {
            s16x8 bk = zf;
            if (lane < 32) bk = ldfrag(sKf + (swz((h * 4 + nt) * 32 + lane) << 3));
            f32x4 cin = {rc[nt][0], rc[nt][1], rc[nt][2], rc[nt][3]};
            f32x4 t = __builtin_amdgcn_mfma_f32_16x16x32_bf16(aq, bk, cin, 0, 0, 0);
#pragma unroll
            for (int r = 0; r < 4; ++r) {
                float s = bm[r] ? -1e9f : t[r];
                scores_out[sbase + toff + r * 64 + nt * 16] = s;
                sv[nt][r] = __expf(s);      // masked rows -> exp underflows to 0
            }
            float e = sv[nt][0] + sv[nt][1] + sv[nt][2] + sv[nt][3];
            e += __shfl_xor(e, 16, 64);
            e += __shfl_xor(e, 32, 64);
            Sw[nt] = e;
        }
        // cross-wave column-sum combine. wS region: h0 -> sWA[0:1KB] (extra
        // barrier below); h>=1 -> head (h-1)'s dead K region sKf[(h-1)*2KB].
        float* wS = (h == 0) ? (float*)(smem + 16384) : (float*)(smem + (h - 1) * 2048);
        if (quad == 0) {
#pragma unroll
            for (int nt = 0; nt < 4; ++nt) wS[(nt * 16 + l16) * 4 + w] = Sw[nt];
        }
        __syncthreads();   // the head's single barrier

        float inv[4];
#pragma unroll
        for (int nt = 0; nt < 4; ++nt) {
            float4 vs = *reinterpret_cast<float4*>(&wS[(nt * 16 + l16) * 4]);
            inv[nt] = 1.0f / (vs.x + vs.y + vs.z + vs.w);
        }
        if (h == 0) __syncthreads();   // wS aliases sWA (wave 0's frag rows) at h0 only

        // attn -> PV A-frag layout; wave writes ONLY its own rows (w*2, w*2+1)
#pragma unroll
        for (int nt = 0; nt < 4; ++nt) {
            int k  = nt * 16 + l16;
            int rw = (w * 2 + (k >> 5)) * 64 + (((k >> 3) & 3) << 4) + quad * 4;
#pragma unroll
            for (int r = 0; r < 4; ++r)
                sWA[(swz(rw + r) << 3) + (k & 7)] = f2bf(sv[nt][r] * inv[nt]);
        }
        // PV immediately: same-wave ds write->read, no barrier needed
#pragma unroll
        for (int ki = 0; ki < 2; ++ki) {
            s16x8 ap = ldfrag(sWA + (swz((w * 2 + ki) * 64 + lane) << 3));
            s16x8 bv = ldfrag(sVf + (swz((h * 2 + ki) * 64 + lane) << 3));
            ctx[h] = __builtin_amdgcn_mfma_f32_16x16x32_bf16(ap, bv, ctx[h], 0, 0, 0);
        }
    }
    __syncthreads();   // all attention LDS reads done; sKf/sWA reusable

    // ---------------- fc + residual + layernorm ----------------
    // xres/LN loads issued here; latency hides under ds writes + Wfc staging
    float xres[4][4], scl[4], bia[4];
    {
        const float* xp = Xq + base64 + toff;
#pragma unroll
        for (int nt = 0; nt < 4; ++nt) {
#pragma unroll
            for (int r = 0; r < 4; ++r) xres[nt][r] = xp[r * 64 + nt * 16];
            scl[nt] = lnS[nt * 16 + l16];
            bia[nt] = lnB[nt * 16 + l16];
        }
    }
    // ctx -> fc A-frag layout into sKf (dead); Wfc B-frags into sWA (dead)
#pragma unroll
    for (int hh = 0; hh < 4; ++hh) {
        int c    = hh * 16 + l16;
        int rowb = (w * 2 + (c >> 5)) * 64 + (((c >> 3) & 3) << 4) + quad * 4;
#pragma unroll
        for (int r = 0; r < 4; ++r)
            sKf[(swz(rowb + r) << 3) + (c & 7)] = f2bf(ctx[hh][r]);
    }
    stage_B(Wfc, sWA, tid);
    __syncthreads();

    f32x4 oacc[4];
    {
        s16x8 a0 = ldfrag(sKf + (swz((w * 2 + 0) * 64 + lane) << 3));
        s16x8 a1 = ldfrag(sKf + (swz((w * 2 + 1) * 64 + lane) << 3));
#pragma unroll
        for (int nt = 0; nt < 4; ++nt) {
            f32x4 a = {0.f, 0.f, 0.f, 0.f};
            s16x8 b0 = ldfrag(sWA + (swz((nt * 2 + 0) * 64 + lane) << 3));
            s16x8 b1 = ldfrag(sWA + (swz((nt * 2 + 1) * 64 + lane) << 3));
            a = __builtin_amdgcn_mfma_f32_16x16x32_bf16(a0, b0, a, 0, 0, 0);
            a = __builtin_amdgcn_mfma_f32_16x16x32_bf16(a1, b1, a, 0, 0, 0);
            oacc[nt] = a;
        }
    }

#pragma unroll
    for (int r = 0; r < 4; ++r) {
        float px[4], sum = 0.f, sq = 0.f;
#pragma unroll
        for (int nt = 0; nt < 4; ++nt) {
            float x = oacc[nt][r] + xres[nt][r];
            px[nt] = x; sum += x; sq += x * x;
        }
#pragma unroll
        for (int m = 1; m <= 8; m <<= 1) {
            sum += __shfl_xor(sum, m, 64);
            sq  += __shfl_xor(sq,  m, 64);
        }
        float mu   = sum * 0.015625f;
        float var  = sq * 0.015625f - mu * mu;
        float rstd = rsqrtf(var + 1e-5f);
#pragma unroll
        for (int nt = 0; nt < 4; ++nt) {
            out[base64 + toff + r * 64 + nt * 16] = (px[nt] - mu) * rstd * scl[nt] + bia[nt];
        }
    }
}

extern "C" void kernel_launch(void* const* d_in, const int* in_sizes, int n_in,
                              void* d_out, int out_size, void* d_ws, size_t ws_size,
                              hipStream_t stream) {
    const float* Xq   = (const float*)d_in[0];
    const float* Xk   = (const float*)d_in[1];
    const float* Xv   = (const float*)d_in[2];
    const float* msk  = (const float*)d_in[3];
    const float* res  = (const float*)d_in[4];
    const float* Wq   = (const float*)d_in[5];
    const float* Wk   = (const float*)d_in[6];
    const float* Wv   = (const float*)d_in[7];
    const float* Wfc  = (const float*)d_in[8];
    const float* lnS  = (const float*)d_in[9];
    const float* lnB  = (const float*)d_in[10];
    float* out    = (float*)d_out;
    float* scores = out + OUT_ELEMS;
    mta_kernel<<<BN, 256, 0, stream>>>(Xq, Xk, Xv, msk, res, Wq, Wk, Wv, Wfc,
                                       lnS, lnB, out, scores);
}